// Round 4
// baseline (579.719 us; speedup 1.0000x reference)
//
#include <hip/hip_runtime.h>
#include <cstdint>
#include <cstddef>

// MFMA fragment types (gfx950)
typedef __attribute__((ext_vector_type(8))) short short8;   // 8 bf16 (4 VGPRs)
typedef __attribute__((ext_vector_type(4))) short short4v;  // 4 bf16 (2 VGPRs)
typedef __attribute__((ext_vector_type(4))) float f32x4;    // 4 fp32 acc

// layer-2 uses the legacy-shape 16x16x16 bf16 MFMA (K=16: A/B frag k = 4*quad+j
// — matches the C-layout of the swapped layer-1 output exactly, so h never
// leaves registers). HIP compiles this TU twice; the AMDGCN builtins only
// exist on the DEVICE pass (round-3 failure: #error fired on the host pass).
#if !defined(__HIP_DEVICE_COMPILE__)
  // host pass: macro must parse but is never executed
  #define MFMA16(A, B, C) (C)
#elif __has_builtin(__builtin_amdgcn_mfma_f32_16x16x16bf16_1k)
  #define MFMA16(A, B, C) __builtin_amdgcn_mfma_f32_16x16x16bf16_1k((A), (B), (C), 0, 0, 0)
#elif __has_builtin(__builtin_amdgcn_mfma_f32_16x16x16_bf16)
  #define MFMA16(A, B, C) __builtin_amdgcn_mfma_f32_16x16x16_bf16((A), (B), (C), 0, 0, 0)
#else
  #error "no 16x16x16 bf16 MFMA builtin on device"
#endif

// float -> bf16 bits, round-to-nearest-even (inputs are finite normals)
__device__ __forceinline__ unsigned short f2bf(float f) {
    union { float f; unsigned int u; } v;
    v.f = f;
    unsigned int r = v.u + 0x7fffu + ((v.u >> 16) & 1u);
    return (unsigned short)(r >> 16);
}

// W1 fragment swizzle (16x16x32 A-operand of the SWAPPED layer-1 mfma):
// fragment (ks, nt), lane L, 8 contiguous bf16 hold
//   W1[k = ks*32 + (L>>4)*8 + j][n = nt*16 + (L&15)],  j = 0..7
__device__ __forceinline__ int bswz(int k, int n) {
    const int ks = k >> 5, quad = (k >> 3) & 3, j = k & 7;
    const int nt = n >> 4, lo = n & 15;
    return ((((ks << 2) + nt) << 6) + (quad << 4) + lo) * 8 + j;
}

// W2 fragment swizzle (16x16x16 A-operand of the SWAPPED layer-2 mfma):
// fragment (ks2, nt2), lane L, 4 contiguous bf16 hold
//   W2[k = ks2*16 + (L>>4)*4 + j][n = nt2*16 + (L&15)],  j = 0..3
__device__ __forceinline__ int w2swz(int k, int n) {
    const int ks2 = k >> 4, q = (k >> 2) & 3, j = k & 3;
    const int nt2 = n >> 4, lo = n & 15;
    return ((((ks2 << 2) + nt2) << 6) + (q << 4) + lo) * 4 + j;
}

// 512 threads = 8 waves x 32 edges. LDS 40960 B -> 3 blocks/CU by LDS.
// waves_per_eu(4,6): min 4 (<=128 VGPR, guaranteed spill-free) so the
// allocator is never FORCED to spill; max 6 (24 waves/CU, the LDS limit)
// so it stops shrinking registers once 6 waves/EU is reachable — forbids
// round-1's pathological squeeze to 64 VGPR + scratch spills.
__global__ void __attribute__((amdgpu_waves_per_eu(4, 6))) __launch_bounds__(512)
megnet_edge(const float* __restrict__ g_src,
            const float* __restrict__ g_dst,
            const float* __restrict__ g_ea,
            const float* __restrict__ g_u,
            const int*   __restrict__ g_batch,
            const float* __restrict__ g_W1,
            const float* __restrict__ g_b1,
            const float* __restrict__ g_W2,
            const float* __restrict__ g_b2,
            float* __restrict__ g_out,
            int E, int NG, int ntiles)
{
    __shared__ unsigned short w1s[256 * 64];   // 32 KB swizzled bf16 W1 fragments
    __shared__ unsigned short w2s[64 * 64];    //  8 KB swizzled bf16 W2 fragments

    const int tid = threadIdx.x;

    // ---- stage + swizzle W1 (256x64 fp32 -> bf16 fragments) ----
    for (int i = tid; i < 4096; i += 512) {
        const int flat = i << 2;
        const int k = flat >> 6, n0 = flat & 63;
        const float* p = g_W1 + flat;
        #pragma unroll
        for (int c = 0; c < 4; ++c)
            w1s[bswz(k, n0 + c)] = f2bf(p[c]);
    }
    // ---- stage + swizzle W2 (64x64) ----
    for (int i = tid; i < 1024; i += 512) {
        const int flat = i << 2;
        const int k = flat >> 6, n0 = flat & 63;
        const float* p = g_W2 + flat;
        #pragma unroll
        for (int c = 0; c < 4; ++c)
            w2s[w2swz(k, n0 + c)] = f2bf(p[c]);
    }
    __syncthreads();
    // weights are read-only from here: NO barrier inside the tile loop

    const int lane = tid & 63;
    const int wave = tid >> 6;
    const int lo   = lane & 15;
    const int quad = lane >> 4;
    const short8*  w1f = (const short8*)w1s;
    const short4v* w2f = (const short4v*)w2s;

    for (int tile = blockIdx.x; tile < ntiles; tile += gridDim.x) {
        const int e_base = tile * 256 + wave * 32;

        // per-mt row offsets (fp32 elements; rc*64 < 2^31 so int is fine)
        int off[2], uoff[2];
        #pragma unroll
        for (int mt = 0; mt < 2; ++mt) {
            const int row = e_base + (mt << 4) + lo;
            const int rc  = row < E ? row : E - 1;
            off[mt] = rc << 6;
            int g = g_batch[rc];
            g = g < 0 ? 0 : (g >= NG ? NG - 1 : g);
            uoff[mt] = g << 6;
        }

        // ===== layer 1 (swapped): h^T-tile = mfma(W1-frag, X-frag) ============
        // result layout: lane holds h[edge = e_base+16mt+lo][n = 16nt+4quad+r]
        // bias b1 folded into acc init (b1[n], n = 16nt + 4quad + r)
        f32x4 acc[2][4];
        #pragma unroll
        for (int nt = 0; nt < 4; ++nt) {
            const float4 b = *reinterpret_cast<const float4*>(
                g_b1 + (nt << 4) + (quad << 2));
            acc[0][nt] = (f32x4){b.x, b.y, b.z, b.w};
            acc[1][nt] = (f32x4){b.x, b.y, b.z, b.w};
        }

        #pragma unroll
        for (int ks = 0; ks < 8; ++ks) {
            const int seg = ks >> 1;                       // concat source
            const int co  = ((ks & 1) << 5) + (quad << 3); // col offset in segment
            short8 xf[2];
            #pragma unroll
            for (int mt = 0; mt < 2; ++mt) {
                const float* base = seg == 0 ? g_src
                                  : seg == 1 ? g_dst
                                  : seg == 2 ? g_ea : g_u;
                const int o = (seg == 3 ? uoff[mt] : off[mt]) + co;
                const float4 x = *reinterpret_cast<const float4*>(base + o);
                const float4 y = *reinterpret_cast<const float4*>(base + o + 4);
                short8 t;
                t[0] = (short)f2bf(x.x); t[1] = (short)f2bf(x.y);
                t[2] = (short)f2bf(x.z); t[3] = (short)f2bf(x.w);
                t[4] = (short)f2bf(y.x); t[5] = (short)f2bf(y.y);
                t[6] = (short)f2bf(y.z); t[7] = (short)f2bf(y.w);
                xf[mt] = t;
            }
            #pragma unroll
            for (int nt = 0; nt < 4; ++nt) {
                const short8 a = w1f[(((ks << 2) + nt) << 6) + lane];
                #pragma unroll
                for (int mt = 0; mt < 2; ++mt)
                    acc[mt][nt] = __builtin_amdgcn_mfma_f32_16x16x32_bf16(
                        a, xf[mt], acc[mt][nt], 0, 0, 0);
            }
        }

        // ===== relu + pack h to bf16 IN REGISTERS =============================
        // acc[mt][nt][r] = h[16mt+lo][16nt+4quad+r] is exactly the 16x16x16
        // B-fragment layout (k = 4quad + j) with nt<->ks2, r<->j.
        short4v pa[2][4];
        #pragma unroll
        for (int mt = 0; mt < 2; ++mt) {
            #pragma unroll
            for (int nt = 0; nt < 4; ++nt) {
                short4v t;
                #pragma unroll
                for (int r = 0; r < 4; ++r) {
                    float v = acc[mt][nt][r];
                    v = v > 0.f ? v : 0.f;
                    t[r] = (short)f2bf(v);
                }
                pa[mt][nt] = t;
            }
        }

        // ===== layer 2 (swapped): out^T-tile = mfma(W2-frag, h-frag) ==========
        // result layout: lane holds out[e_base+16mt+lo][16nt2+4quad+r]
        // bias b2 folded into acc2 init
        f32x4 acc2[2][4];
        #pragma unroll
        for (int nt2 = 0; nt2 < 4; ++nt2) {
            const float4 b = *reinterpret_cast<const float4*>(
                g_b2 + (nt2 << 4) + (quad << 2));
            acc2[0][nt2] = (f32x4){b.x, b.y, b.z, b.w};
            acc2[1][nt2] = (f32x4){b.x, b.y, b.z, b.w};
        }
        #pragma unroll
        for (int nt2 = 0; nt2 < 4; ++nt2) {
            #pragma unroll
            for (int ks2 = 0; ks2 < 4; ++ks2) {
                const short4v a = w2f[(((ks2 << 2) + nt2) << 6) + lane];
                acc2[0][nt2] = MFMA16(a, pa[0][ks2], acc2[0][nt2]);
                acc2[1][nt2] = MFMA16(a, pa[1][ks2], acc2[1][nt2]);
            }
        }

        // ===== epilogue: relu + fp32 store, float4 per lane ===================
        #pragma unroll
        for (int mt = 0; mt < 2; ++mt) {
            const int row = e_base + (mt << 4) + lo;
            if (row < E) {
                float* op = g_out + (size_t)row * 64 + (quad << 2);
                #pragma unroll
                for (int nt2 = 0; nt2 < 4; ++nt2) {
                    float4 v;
                    v.x = acc2[mt][nt2][0] > 0.f ? acc2[mt][nt2][0] : 0.f;
                    v.y = acc2[mt][nt2][1] > 0.f ? acc2[mt][nt2][1] : 0.f;
                    v.z = acc2[mt][nt2][2] > 0.f ? acc2[mt][nt2][2] : 0.f;
                    v.w = acc2[mt][nt2][3] > 0.f ? acc2[mt][nt2][3] : 0.f;
                    *reinterpret_cast<float4*>(op + (nt2 << 4)) = v;
                }
            }
        }
    }
}

extern "C" void kernel_launch(void* const* d_in, const int* in_sizes, int n_in,
                              void* d_out, int out_size, void* d_ws, size_t ws_size,
                              hipStream_t stream) {
    const float* g_src   = (const float*)d_in[0];
    const float* g_dst   = (const float*)d_in[1];
    const float* g_ea    = (const float*)d_in[2];
    const float* g_u     = (const float*)d_in[3];
    const int*   g_batch = (const int*)  d_in[4];
    const float* g_W1    = (const float*)d_in[5];
    const float* g_b1    = (const float*)d_in[6];
    const float* g_W2    = (const float*)d_in[7];
    const float* g_b2    = (const float*)d_in[8];
    float*       g_out   = (float*)d_out;

    const int E  = in_sizes[0] / 64;        // 500000
    const int NG = in_sizes[3] / 64;        // 1024
    const int ntiles = (E + 255) / 256;     // 1954 tiles of 256 edges

    // persistent grid: 3 blocks/CU (LDS 40960 B) x 256 CUs
    int grid = ntiles < 768 ? ntiles : 768;
    megnet_edge<<<grid, 512, 0, stream>>>(g_src, g_dst, g_ea, g_u, g_batch,
                                          g_W1, g_b1, g_W2, g_b2, g_out,
                                          E, NG, ntiles);
}

// Round 6
// 434.721 us; speedup vs baseline: 1.3335x; 1.3335x over previous
//
#include <hip/hip_runtime.h>
#include <cstdint>
#include <cstddef>

// MFMA fragment types (gfx950)
typedef __attribute__((ext_vector_type(8))) short short8;   // 8 bf16 (4 VGPRs)
typedef __attribute__((ext_vector_type(4))) short short4v;  // 4 bf16 (2 VGPRs)
typedef __attribute__((ext_vector_type(4))) float f32x4;    // 4 fp32 acc

// layer-2 uses the legacy-shape 16x16x16 bf16 MFMA (K=16: A/B frag k = 4*quad+j
// — matches the C-layout of the swapped layer-1 output exactly, so h never
// leaves registers). HIP compiles this TU twice; the AMDGCN builtins only
// exist on the DEVICE pass (round-3 lesson: guard the host pass).
#if !defined(__HIP_DEVICE_COMPILE__)
  #define MFMA16(A, B, C) (C)   // host pass: parse-only, never executed
#elif __has_builtin(__builtin_amdgcn_mfma_f32_16x16x16bf16_1k)
  #define MFMA16(A, B, C) __builtin_amdgcn_mfma_f32_16x16x16bf16_1k((A), (B), (C), 0, 0, 0)
#elif __has_builtin(__builtin_amdgcn_mfma_f32_16x16x16_bf16)
  #define MFMA16(A, B, C) __builtin_amdgcn_mfma_f32_16x16x16_bf16((A), (B), (C), 0, 0, 0)
#else
  #error "no 16x16x16 bf16 MFMA builtin on device"
#endif

// float -> bf16 bits, round-to-nearest-even (inputs are finite normals)
__device__ __forceinline__ unsigned short f2bf(float f) {
    union { float f; unsigned int u; } v;
    v.f = f;
    unsigned int r = v.u + 0x7fffu + ((v.u >> 16) & 1u);
    return (unsigned short)(r >> 16);
}

// W1 fragment swizzle (16x16x32 A-operand of the SWAPPED layer-1 mfma):
// fragment (ks, nt), lane L, 8 contiguous bf16 hold
//   W1[k = ks*32 + (L>>4)*8 + j][n = nt*16 + (L&15)],  j = 0..7
__device__ __forceinline__ int bswz(int k, int n) {
    const int ks = k >> 5, quad = (k >> 3) & 3, j = k & 7;
    const int nt = n >> 4, lo = n & 15;
    return ((((ks << 2) + nt) << 6) + (quad << 4) + lo) * 8 + j;
}

// W2 fragment swizzle (16x16x16 A-operand of the SWAPPED layer-2 mfma):
// fragment (ks2, nt2), lane L, 4 contiguous bf16 hold
//   W2[k = ks2*16 + (L>>4)*4 + j][n = nt2*16 + (L&15)],  j = 0..3
__device__ __forceinline__ int w2swz(int k, int n) {
    const int ks2 = k >> 4, q = (k >> 2) & 3, j = k & 3;
    const int nt2 = n >> 4, lo = n & 15;
    return ((((ks2 << 2) + nt2) << 6) + (q << 4) + lo) * 4 + j;
}

// 256 threads = 4 waves x 32 edges = 128 edges/block. LDS 40960 B -> 4 blocks/CU.
// __launch_bounds__(256, 2): the EXPLICIT min-waves arg is what stops the
// allocator's squeeze-to-64-regs + scratch-spill pathology (rounds 1 & 4:
// wg=512 / no explicit arg / amdgpu_waves_per_eu all produced 64 VGPR + ~260 MB
// scratch traffic; round 0 with (256,2) allocated 88 VGPR, zero scratch).
__global__ void __launch_bounds__(256, 2)
megnet_edge(const float* __restrict__ g_src,
            const float* __restrict__ g_dst,
            const float* __restrict__ g_ea,
            const float* __restrict__ g_u,
            const int*   __restrict__ g_batch,
            const float* __restrict__ g_W1,
            const float* __restrict__ g_b1,
            const float* __restrict__ g_W2,
            const float* __restrict__ g_b2,
            float* __restrict__ g_out,
            int E, int NG, int ntiles)
{
    __shared__ unsigned short w1s[256 * 64];   // 32 KB swizzled bf16 W1 fragments
    __shared__ unsigned short w2s[64 * 64];    //  8 KB swizzled bf16 W2 fragments

    const int tid = threadIdx.x;

    // ---- stage + swizzle W1 (256x64 fp32 -> bf16 fragments) ----
    for (int i = tid; i < 4096; i += 256) {
        const int flat = i << 2;
        const int k = flat >> 6, n0 = flat & 63;
        const float* p = g_W1 + flat;
        #pragma unroll
        for (int c = 0; c < 4; ++c)
            w1s[bswz(k, n0 + c)] = f2bf(p[c]);
    }
    // ---- stage + swizzle W2 (64x64) ----
    for (int i = tid; i < 1024; i += 256) {
        const int flat = i << 2;
        const int k = flat >> 6, n0 = flat & 63;
        const float* p = g_W2 + flat;
        #pragma unroll
        for (int c = 0; c < 4; ++c)
            w2s[w2swz(k, n0 + c)] = f2bf(p[c]);
    }
    __syncthreads();
    // weights are read-only from here: NO barrier inside the tile loop

    const int lane = tid & 63;
    const int wave = tid >> 6;    // 0..3
    const int lo   = lane & 15;
    const int quad = lane >> 4;
    const short8*  w1f = (const short8*)w1s;
    const short4v* w2f = (const short4v*)w2s;

    for (int tile = blockIdx.x; tile < ntiles; tile += gridDim.x) {
        const int e_base = tile * 128 + wave * 32;

        // per-mt row offsets (fp32 elements; rc*64 < 2^31 so int is fine)
        int off[2], uoff[2];
        #pragma unroll
        for (int mt = 0; mt < 2; ++mt) {
            const int row = e_base + (mt << 4) + lo;
            const int rc  = row < E ? row : E - 1;
            off[mt] = rc << 6;
            int g = g_batch[rc];
            g = g < 0 ? 0 : (g >= NG ? NG - 1 : g);
            uoff[mt] = g << 6;
        }

        // ===== layer 1 (swapped): h^T-tile = mfma(W1-frag, X-frag) ============
        // result layout: lane holds h[edge = e_base+16mt+lo][n = 16nt+4quad+r]
        // bias b1 folded into acc init (b1[n], n = 16nt + 4quad + r)
        f32x4 acc[2][4];
        #pragma unroll
        for (int nt = 0; nt < 4; ++nt) {
            const float4 b = *reinterpret_cast<const float4*>(
                g_b1 + (nt << 4) + (quad << 2));
            acc[0][nt] = (f32x4){b.x, b.y, b.z, b.w};
            acc[1][nt] = (f32x4){b.x, b.y, b.z, b.w};
        }

        #pragma unroll
        for (int ks = 0; ks < 8; ++ks) {
            const int seg = ks >> 1;                       // concat source
            const int co  = ((ks & 1) << 5) + (quad << 3); // col offset in segment
            short8 xf[2];
            #pragma unroll
            for (int mt = 0; mt < 2; ++mt) {
                const float* base = seg == 0 ? g_src
                                  : seg == 1 ? g_dst
                                  : seg == 2 ? g_ea : g_u;
                const int o = (seg == 3 ? uoff[mt] : off[mt]) + co;
                const float4 x = *reinterpret_cast<const float4*>(base + o);
                const float4 y = *reinterpret_cast<const float4*>(base + o + 4);
                short8 t;
                t[0] = (short)f2bf(x.x); t[1] = (short)f2bf(x.y);
                t[2] = (short)f2bf(x.z); t[3] = (short)f2bf(x.w);
                t[4] = (short)f2bf(y.x); t[5] = (short)f2bf(y.y);
                t[6] = (short)f2bf(y.z); t[7] = (short)f2bf(y.w);
                xf[mt] = t;
            }
            #pragma unroll
            for (int nt = 0; nt < 4; ++nt) {
                const short8 a = w1f[(((ks << 2) + nt) << 6) + lane];
                #pragma unroll
                for (int mt = 0; mt < 2; ++mt)
                    acc[mt][nt] = __builtin_amdgcn_mfma_f32_16x16x32_bf16(
                        a, xf[mt], acc[mt][nt], 0, 0, 0);
            }
        }

        // ===== relu + pack h to bf16 IN REGISTERS =============================
        // acc[mt][nt][r] = h[16mt+lo][16nt+4quad+r] is exactly the 16x16x16
        // B-fragment layout (k = 4quad + j) with nt<->ks2, r<->j.
        short4v pa[2][4];
        #pragma unroll
        for (int mt = 0; mt < 2; ++mt) {
            #pragma unroll
            for (int nt = 0; nt < 4; ++nt) {
                short4v t;
                #pragma unroll
                for (int r = 0; r < 4; ++r) {
                    float v = acc[mt][nt][r];
                    v = v > 0.f ? v : 0.f;
                    t[r] = (short)f2bf(v);
                }
                pa[mt][nt] = t;
            }
        }

        // ===== layer 2 (swapped): out^T-tile = mfma(W2-frag, h-frag) ==========
        // result layout: lane holds out[e_base+16mt+lo][16nt2+4quad+r]
        // bias b2 folded into acc2 init
        f32x4 acc2[2][4];
        #pragma unroll
        for (int nt2 = 0; nt2 < 4; ++nt2) {
            const float4 b = *reinterpret_cast<const float4*>(
                g_b2 + (nt2 << 4) + (quad << 2));
            acc2[0][nt2] = (f32x4){b.x, b.y, b.z, b.w};
            acc2[1][nt2] = (f32x4){b.x, b.y, b.z, b.w};
        }
        #pragma unroll
        for (int nt2 = 0; nt2 < 4; ++nt2) {
            #pragma unroll
            for (int ks2 = 0; ks2 < 4; ++ks2) {
                const short4v a = w2f[(((ks2 << 2) + nt2) << 6) + lane];
                acc2[0][nt2] = MFMA16(a, pa[0][ks2], acc2[0][nt2]);
                acc2[1][nt2] = MFMA16(a, pa[1][ks2], acc2[1][nt2]);
            }
        }

        // ===== epilogue: relu + fp32 store, float4 per lane ===================
        #pragma unroll
        for (int mt = 0; mt < 2; ++mt) {
            const int row = e_base + (mt << 4) + lo;
            if (row < E) {
                float* op = g_out + (size_t)row * 64 + (quad << 2);
                #pragma unroll
                for (int nt2 = 0; nt2 < 4; ++nt2) {
                    float4 v;
                    v.x = acc2[mt][nt2][0] > 0.f ? acc2[mt][nt2][0] : 0.f;
                    v.y = acc2[mt][nt2][1] > 0.f ? acc2[mt][nt2][1] : 0.f;
                    v.z = acc2[mt][nt2][2] > 0.f ? acc2[mt][nt2][2] : 0.f;
                    v.w = acc2[mt][nt2][3] > 0.f ? acc2[mt][nt2][3] : 0.f;
                    *reinterpret_cast<float4*>(op + (nt2 << 4)) = v;
                }
            }
        }
    }
}

extern "C" void kernel_launch(void* const* d_in, const int* in_sizes, int n_in,
                              void* d_out, int out_size, void* d_ws, size_t ws_size,
                              hipStream_t stream) {
    const float* g_src   = (const float*)d_in[0];
    const float* g_dst   = (const float*)d_in[1];
    const float* g_ea    = (const float*)d_in[2];
    const float* g_u     = (const float*)d_in[3];
    const int*   g_batch = (const int*)  d_in[4];
    const float* g_W1    = (const float*)d_in[5];
    const float* g_b1    = (const float*)d_in[6];
    const float* g_W2    = (const float*)d_in[7];
    const float* g_b2    = (const float*)d_in[8];
    float*       g_out   = (float*)d_out;

    const int E  = in_sizes[0] / 64;        // 500000
    const int NG = in_sizes[3] / 64;        // 1024
    const int ntiles = (E + 127) / 128;     // 3907 tiles of 128 edges

    // persistent grid: 4 blocks/CU (LDS 40960 B) x 256 CUs
    int grid = ntiles < 1024 ? ntiles : 1024;
    megnet_edge<<<grid, 256, 0, stream>>>(g_src, g_dst, g_ea, g_u, g_batch,
                                          g_W1, g_b1, g_W2, g_b2, g_out,
                                          E, NG, ntiles);
}